// Round 1
// baseline (680.263 us; speedup 1.0000x reference)
//
#include <hip/hip_runtime.h>

#define S_LEN 1024
#define DMODEL 768
#define NHEAD 12
#define HDIM 64
#define SCALE 0.125f
#define INF_ 1000000.0f
#define BI 8

// ---------------- generic fp32 tiled GEMM -------------------------------
// C = A(M,K) @ B(K,N) * scale + bias
// mode 0: C[row*N+col]
// mode 1: C[((row/1024)*768 + col)*1024 + row%1024]   (k transposed per batch)
// mode 2: C[col*2048 + row]                           (r transposed)
__global__ __launch_bounds__(256) void gemm_f32(
    const float* __restrict__ A, const float* __restrict__ B,
    const float* __restrict__ bias, float* __restrict__ C,
    int M, int N, int K, float scale, int mode)
{
    __shared__ float As[64][16];
    __shared__ float Bs[16][64];
    int tx = threadIdx.x, ty = threadIdx.y;
    int tid = ty * 16 + tx;
    int rowBase = blockIdx.y * 64;
    int colBase = blockIdx.x * 64;
    float acc[4][4] = {};
    for (int k0 = 0; k0 < K; k0 += 16) {
#pragma unroll
        for (int l = 0; l < 4; ++l) {
            int e = tid + l * 256;
            int i = e >> 4, kk = e & 15;
            As[i][kk] = A[(size_t)(rowBase + i) * K + k0 + kk];
        }
#pragma unroll
        for (int l = 0; l < 4; ++l) {
            int e = tid + l * 256;
            int kk = e >> 6, j = e & 63;
            Bs[kk][j] = B[(size_t)(k0 + kk) * N + colBase + j];
        }
        __syncthreads();
#pragma unroll
        for (int kk = 0; kk < 16; ++kk) {
            float ra[4], rb[4];
#pragma unroll
            for (int a = 0; a < 4; ++a) ra[a] = As[ty + 16 * a][kk];
#pragma unroll
            for (int b4 = 0; b4 < 4; ++b4) rb[b4] = Bs[kk][tx + 16 * b4];
#pragma unroll
            for (int a = 0; a < 4; ++a)
#pragma unroll
                for (int b4 = 0; b4 < 4; ++b4) acc[a][b4] += ra[a] * rb[b4];
        }
        __syncthreads();
    }
#pragma unroll
    for (int a = 0; a < 4; ++a) {
        int row = rowBase + ty + 16 * a;
#pragma unroll
        for (int b4 = 0; b4 < 4; ++b4) {
            int col = colBase + tx + 16 * b4;
            float v = acc[a][b4] * scale + (bias ? bias[col] : 0.0f);
            if (mode == 0) {
                C[(size_t)row * N + col] = v;
            } else if (mode == 1) {
                int b = row >> 10, j = row & 1023;
                C[((size_t)b * 768 + col) * 1024 + j] = v;
            } else {
                C[(size_t)col * 2048 + row] = v;
            }
        }
    }
}

// ---------------- fused attention ---------------------------------------
// grid: (S/BI, NHEAD, BATCH), block 256
__global__ __launch_bounds__(256) void attn_kernel(
    const float* __restrict__ q_head,   // (B*S, 768)  pre-scaled
    const float* __restrict__ kt,       // (B, 768, S)
    const float* __restrict__ v_head,   // (B*S, 768)
    const float* __restrict__ rt,       // (768, 2048)
    const float* __restrict__ r_w_bias, // (768)
    const float* __restrict__ r_r_bias,
    const float* __restrict__ r_s_bias,
    const float* __restrict__ seg,      // (2, 768)
    const float* __restrict__ cls_mask, // (S, S)
    const int* __restrict__ tt_mat,     // (B, S, S)
    const int* __restrict__ amask,      // (B, S)
    float* __restrict__ attn_vec)       // (B*S, 768)
{
    __shared__ float sQw[BI][64], sQr[BI][64], sQs[BI][64];
    __shared__ float sS[BI][1024];
    __shared__ float sPV[4][BI][64];
    __shared__ float sDiff[BI], sSame[BI];
    __shared__ float sRedA[4], sRedB[4];

    int tid = threadIdx.x;
    int i0 = blockIdx.x * BI;
    int n = blockIdx.y;
    int b = blockIdx.z;
    int wave = tid >> 6, lane = tid & 63;

    // stage q variants
    for (int e = tid; e < BI * 64; e += 256) {
        int r = e >> 6, h = e & 63;
        float q = q_head[(size_t)(b * S_LEN + i0 + r) * 768 + n * 64 + h];
        sQw[r][h] = q + r_w_bias[n * 64 + h] * SCALE;
        sQr[r][h] = q + r_r_bias[n * 64 + h] * SCALE;
        sQs[r][h] = q + r_s_bias[n * 64 + h] * SCALE;
    }
    __syncthreads();

    // per-row diff/same segment dots (wave w handles rows w, w+4)
    for (int r = wave; r < BI; r += 4) {
        float qs = sQs[r][lane];
        float d = qs * seg[n * 64 + lane];
        float sm = qs * seg[768 + n * 64 + lane];
#pragma unroll
        for (int off = 32; off >= 1; off >>= 1) {
            d += __shfl_xor(d, off);
            sm += __shfl_xor(sm, off);
        }
        if (lane == 0) { sDiff[r] = d; sSame[r] = sm; }
    }
    __syncthreads();

    const float* ktb = kt + ((size_t)b * 768 + n * 64) * 1024;
    const float* rtb = rt + (size_t)(n * 64) * 2048;
    int tbase = S_LEN - i0;

    // scores
    for (int l = 0; l < 4; ++l) {
        int j = tid + l * 256;
        float content[BI] = {};
        float posv[BI] = {};
        for (int h = 0; h < 64; ++h) {
            float kv = ktb[h * 1024 + j];
#pragma unroll
            for (int r = 0; r < BI; ++r) content[r] += sQw[r][h] * kv;
        }
        for (int h = 0; h < 64; ++h) {
            const float* rrow = rtb + (size_t)h * 2048 + tbase + j;
#pragma unroll
            for (int r = 0; r < BI; ++r) posv[r] += sQr[r][h] * rrow[-r];
        }
        float am = (float)amask[b * S_LEN + j];
        float maskterm = -INF_ * (1.0f - am);
#pragma unroll
        for (int r = 0; r < BI; ++r) {
            int i = i0 + r;
            float cls = cls_mask[(size_t)i * S_LEN + j];
            int tt = tt_mat[((size_t)b * S_LEN + i) * S_LEN + j];
            float ttv = tt ? sSame[r] : sDiff[r];
            sS[r][j] = content[r] + (posv[r] + ttv) * cls + maskterm;
        }
    }
    __syncthreads();

    // softmax per row
    for (int r = 0; r < BI; ++r) {
        float m = -3.0e38f;
#pragma unroll
        for (int l = 0; l < 4; ++l) m = fmaxf(m, sS[r][tid + 256 * l]);
#pragma unroll
        for (int off = 32; off >= 1; off >>= 1) m = fmaxf(m, __shfl_xor(m, off));
        if (lane == 0) sRedA[wave] = m;
        __syncthreads();
        m = fmaxf(fmaxf(sRedA[0], sRedA[1]), fmaxf(sRedA[2], sRedA[3]));
        float sum = 0.0f;
#pragma unroll
        for (int l = 0; l < 4; ++l) {
            float e = __expf(sS[r][tid + 256 * l] - m);
            sS[r][tid + 256 * l] = e;
            sum += e;
        }
#pragma unroll
        for (int off = 32; off >= 1; off >>= 1) sum += __shfl_xor(sum, off);
        if (lane == 0) sRedB[wave] = sum;
        __syncthreads();
        float inv = 1.0f / (sRedB[0] + sRedB[1] + sRedB[2] + sRedB[3]);
#pragma unroll
        for (int l = 0; l < 4; ++l) sS[r][tid + 256 * l] *= inv;
    }
    __syncthreads();

    // PV: thread (h = tid&63, jc = tid>>6) accumulates 256 j's
    {
        int h = tid & 63, jc = tid >> 6;
        const float* vb = v_head + (size_t)(b * S_LEN + jc * 256) * 768 + n * 64 + h;
        float acc[BI] = {};
        for (int jj = 0; jj < 256; ++jj) {
            float vv = vb[(size_t)jj * 768];
            int j = jc * 256 + jj;
#pragma unroll
            for (int r = 0; r < BI; ++r) acc[r] += sS[r][j] * vv;
        }
#pragma unroll
        for (int r = 0; r < BI; ++r) sPV[jc][r][h] = acc[r];
    }
    __syncthreads();
    for (int e = tid; e < BI * 64; e += 256) {
        int r = e >> 6, h = e & 63;
        float v = sPV[0][r][h] + sPV[1][r][h] + sPV[2][r][h] + sPV[3][r][h];
        attn_vec[(size_t)(b * S_LEN + i0 + r) * 768 + n * 64 + h] = v;
    }
}

// ---------------- residual + layernorm ----------------------------------
__global__ __launch_bounds__(256) void out_ln_kernel(
    const float* __restrict__ query, const float* __restrict__ attn_out,
    const float* __restrict__ g, const float* __restrict__ beta,
    float* __restrict__ out)
{
    __shared__ float sx[768];
    __shared__ float sRed[4];
    int row = blockIdx.x, tid = threadIdx.x;
    int wave = tid >> 6, lane = tid & 63;
    float lsum = 0.0f;
    for (int c = tid; c < 768; c += 256) {
        float x = query[(size_t)row * 768 + c] + attn_out[(size_t)row * 768 + c];
        sx[c] = x;
        lsum += x;
    }
#pragma unroll
    for (int off = 32; off >= 1; off >>= 1) lsum += __shfl_xor(lsum, off);
    if (lane == 0) sRed[wave] = lsum;
    __syncthreads();
    float mu = (sRed[0] + sRed[1] + sRed[2] + sRed[3]) * (1.0f / 768.0f);
    float lvar = 0.0f;
    for (int c = tid; c < 768; c += 256) {
        float d = sx[c] - mu;
        lvar += d * d;
    }
#pragma unroll
    for (int off = 32; off >= 1; off >>= 1) lvar += __shfl_xor(lvar, off);
    __syncthreads();
    if (lane == 0) sRed[wave] = lvar;
    __syncthreads();
    float var = (sRed[0] + sRed[1] + sRed[2] + sRed[3]) * (1.0f / 768.0f);
    float rstd = rsqrtf(var + 1e-9f);
    for (int c = tid; c < 768; c += 256)
        out[(size_t)row * 768 + c] = (sx[c] - mu) * rstd * g[c] + beta[c];
}

extern "C" void kernel_launch(void* const* d_in, const int* in_sizes, int n_in,
                              void* d_out, int out_size, void* d_ws, size_t ws_size,
                              hipStream_t stream)
{
    const float* query = (const float*)d_in[0];
    const float* key   = (const float*)d_in[1];
    const float* value = (const float*)d_in[2];
    const float* r     = (const float*)d_in[3];
    const float* cls_mask = (const float*)d_in[4];
    const int*   tt_mat   = (const int*)d_in[5];
    const int*   amask    = (const int*)d_in[6];
    const float* wq  = (const float*)d_in[7];
    const float* wk  = (const float*)d_in[8];
    const float* bk  = (const float*)d_in[9];
    const float* wv  = (const float*)d_in[10];
    const float* bv  = (const float*)d_in[11];
    const float* rwb = (const float*)d_in[12];
    const float* rrb = (const float*)d_in[13];
    const float* rsb = (const float*)d_in[14];
    const float* rk  = (const float*)d_in[15];
    const float* seg = (const float*)d_in[16];
    const float* wo  = (const float*)d_in[17];
    const float* bo  = (const float*)d_in[18];
    const float* lng = (const float*)d_in[19];
    const float* lnb = (const float*)d_in[20];
    float* out = (float*)d_out;

    float* ws = (float*)d_ws;
    const size_t SEG_ = (size_t)2048 * 768;
    float* q_head   = ws;
    float* kt       = ws + SEG_;
    float* v_head   = ws + 2 * SEG_;
    float* rt       = ws + 3 * SEG_;
    float* attn_vec = ws + 4 * SEG_;
    float* attn_out = ws + 5 * SEG_;

    dim3 gblk(16, 16);
    dim3 ggrid(12, 32);
    hipLaunchKernelGGL(gemm_f32, ggrid, gblk, 0, stream, query, wq, (const float*)nullptr, q_head, 2048, 768, 768, SCALE, 0);
    hipLaunchKernelGGL(gemm_f32, ggrid, gblk, 0, stream, key, wk, bk, kt, 2048, 768, 768, 1.0f, 1);
    hipLaunchKernelGGL(gemm_f32, ggrid, gblk, 0, stream, value, wv, bv, v_head, 2048, 768, 768, 1.0f, 0);
    hipLaunchKernelGGL(gemm_f32, ggrid, gblk, 0, stream, r, rk, (const float*)nullptr, rt, 2048, 768, 768, 1.0f, 2);

    hipLaunchKernelGGL(attn_kernel, dim3(S_LEN / BI, NHEAD, 2), dim3(256), 0, stream,
                       q_head, kt, v_head, rt, rwb, rrb, rsb, seg, cls_mask, tt_mat, amask, attn_vec);

    hipLaunchKernelGGL(gemm_f32, ggrid, gblk, 0, stream, attn_vec, wo, bo, attn_out, 2048, 768, 768, 1.0f, 0);
    hipLaunchKernelGGL(out_ln_kernel, dim3(2048), dim3(256), 0, stream, query, attn_out, lng, lnb, out);
}

// Round 2
// 235.153 us; speedup vs baseline: 2.8929x; 2.8929x over previous
//
#include <hip/hip_runtime.h>

#define S_LEN 1024
#define NHEAD 12
#define SCALE 0.125f
#define INF_ 1000000.0f
#define TBW 1056

typedef __attribute__((ext_vector_type(8))) short bfrag;
typedef __attribute__((ext_vector_type(4))) float f32x4;
typedef unsigned short ushort_t;
typedef unsigned int uint_t;

__device__ inline ushort_t f2bf(float f) {
    union { float f; uint_t u; } v; v.f = f;
    uint_t u = v.u;
    return (ushort_t)((u + 0x7fffu + ((u >> 16) & 1u)) >> 16);
}
__device__ inline float bf2f(ushort_t h) {
    union { uint_t u; float f; } v; v.u = ((uint_t)h) << 16;
    return v.f;
}

// ---------------- fp32 -> bf16 elementwise ------------------------------
__global__ __launch_bounds__(256) void cvt_bf16(const float* __restrict__ src,
                                                ushort_t* __restrict__ dst, int n) {
    int i = (blockIdx.x * 256 + threadIdx.x) * 4;
    if (i + 3 < n) {
        float4 v = *(const float4*)&src[i];
        ushort_t o0 = f2bf(v.x), o1 = f2bf(v.y), o2 = f2bf(v.z), o3 = f2bf(v.w);
        dst[i] = o0; dst[i + 1] = o1; dst[i + 2] = o2; dst[i + 3] = o3;
    }
}

// ---------------- fp32 (768x768) -> bf16 transposed ---------------------
__global__ __launch_bounds__(256) void tcvt(const float* __restrict__ src,
                                            ushort_t* __restrict__ dst) {
    __shared__ float tile[64][65];
    int bx = blockIdx.x * 64, by = blockIdx.y * 64;
    for (int e = threadIdx.x; e < 4096; e += 256) {
        int r = e >> 6, c = e & 63;
        tile[r][c] = src[(size_t)(by + r) * 768 + bx + c];
    }
    __syncthreads();
    for (int e = threadIdx.x; e < 4096; e += 256) {
        int r = e >> 6, c = e & 63;
        dst[(size_t)(bx + r) * 768 + by + c] = f2bf(tile[c][r]);
    }
}

// ---------------- bf16 MFMA GEMM  (M=2048, N=768, K=768) ----------------
// A (2048,768) bf16 row-major; BT (768,768) bf16 [n][k].
// mode 0: Cf[row*768+col] = acc*scale + bias
// mode 1: Ch[row*768+col] = bf16(acc + bias)
// mode 2: Ch[((row>>10)*768+col)*1024 + (row&1023)] = bf16(acc + bias)
__global__ __launch_bounds__(256) void gemm_mfma(
    const ushort_t* __restrict__ A, const ushort_t* __restrict__ BT,
    const float* __restrict__ bias, float* __restrict__ Cf,
    ushort_t* __restrict__ Ch, float scale, int mode)
{
    __shared__ __align__(16) ushort_t As[64 * 40];
    __shared__ __align__(16) ushort_t Bs[64 * 40];
    int tid = threadIdx.x;
    int w = tid >> 6, lane = tid & 63, l15 = lane & 15, l4 = lane >> 4;
    int rowBase = blockIdx.x * 64, colBase = blockIdx.y * 64;
    int wm = w >> 1, wn = w & 1;
    f32x4 acc[2][2] = {{{0,0,0,0},{0,0,0,0}},{{0,0,0,0},{0,0,0,0}}};
    int srow = tid >> 2, schunk = (tid & 3) * 8;
    for (int k0 = 0; k0 < 768; k0 += 32) {
        __syncthreads();
        *(uint4*)&As[srow * 40 + schunk] =
            *(const uint4*)&A[(size_t)(rowBase + srow) * 768 + k0 + schunk];
        *(uint4*)&Bs[srow * 40 + schunk] =
            *(const uint4*)&BT[(size_t)(colBase + srow) * 768 + k0 + schunk];
        __syncthreads();
        bfrag bfr[2];
#pragma unroll
        for (int nf = 0; nf < 2; ++nf)
            bfr[nf] = *(const bfrag*)&Bs[(wn * 32 + nf * 16 + l15) * 40 + l4 * 8];
#pragma unroll
        for (int mf = 0; mf < 2; ++mf) {
            bfrag af = *(const bfrag*)&As[(wm * 32 + mf * 16 + l15) * 40 + l4 * 8];
#pragma unroll
            for (int nf = 0; nf < 2; ++nf)
                acc[mf][nf] = __builtin_amdgcn_mfma_f32_16x16x32_bf16(af, bfr[nf], acc[mf][nf], 0, 0, 0);
        }
    }
#pragma unroll
    for (int mf = 0; mf < 2; ++mf)
#pragma unroll
        for (int nf = 0; nf < 2; ++nf)
#pragma unroll
            for (int rg = 0; rg < 4; ++rg) {
                int row = rowBase + wm * 32 + mf * 16 + l4 * 4 + rg;
                int col = colBase + wn * 32 + nf * 16 + l15;
                float v = acc[mf][nf][rg] * scale + (bias ? bias[col] : 0.0f);
                if (mode == 0) Cf[(size_t)row * 768 + col] = v;
                else if (mode == 1) Ch[(size_t)row * 768 + col] = f2bf(v);
                else Ch[((size_t)(row >> 10) * 768 + col) * 1024 + (row & 1023)] = f2bf(v);
            }
}

// ---------------- fused attention (MFMA) --------------------------------
// grid (32, 12, 2), block 256 (4 waves). Each block: 32 q-rows, one (b,n).
__global__ __launch_bounds__(256) void attn_mfma(
    const float* __restrict__ qh,      // (B*S,768) f32, pre-scaled
    const ushort_t* __restrict__ kh,   // (B*S,768) bf16
    const ushort_t* __restrict__ vt,   // (B,768,S) bf16
    const ushort_t* __restrict__ rh,   // (2064,768) bf16
    const float* __restrict__ rwb, const float* __restrict__ rrb,
    const float* __restrict__ rsb, const float* __restrict__ seg,
    const float* __restrict__ cls_mask, const int* __restrict__ tt_mat,
    const int* __restrict__ amask,
    ushort_t* __restrict__ av)         // (B*S,768) bf16
{
    __shared__ __align__(16) ushort_t sQw[32 * 64];
    __shared__ __align__(16) ushort_t sQr[32 * 64];
    __shared__ __align__(16) ushort_t sT[32 * TBW];
    __shared__ __align__(16) ushort_t sS[32 * 1024];
    __shared__ float sAm[1024];
    __shared__ float sDiff[32], sSame[32];

    const int tid = threadIdx.x;
    const int w = tid >> 6, lane = tid & 63;
    const int l15 = lane & 15, l4 = lane >> 4;
    const int i0 = blockIdx.x * 32;
    const int n = blockIdx.y;
    const int b = blockIdx.z;

    // ---- stage Q variants + seg dots + amask ----
    {
        const float* qbase = qh + ((size_t)(b * S_LEN + i0)) * 768 + n * 64;
        float s0 = seg[n * 64 + lane], s1 = seg[768 + n * 64 + lane];
        float bw = rwb[n * 64 + lane] * SCALE;
        float br = rrb[n * 64 + lane] * SCALE;
        float bs = rsb[n * 64 + lane] * SCALE;
        for (int l = 0; l < 8; ++l) {
            int r = w + 4 * l;
            float qv = qbase[(size_t)r * 768 + lane];
            sQw[r * 64 + lane] = f2bf(qv + bw);
            sQr[r * 64 + lane] = f2bf(qv + br);
            float qs = qv + bs;
            float d = qs * s0, sm = qs * s1;
#pragma unroll
            for (int off = 32; off >= 1; off >>= 1) {
                d += __shfl_xor(d, off);
                sm += __shfl_xor(sm, off);
            }
            if (lane == 0) { sDiff[r] = d; sSame[r] = sm; }
        }
        for (int j = tid; j < 1024; j += 256)
            sAm[j] = -INF_ * (1.0f - (float)amask[b * S_LEN + j]);
    }
    __syncthreads();

    const int tstart = 993 - i0;  // S - i0 - 31

    // ---- Phase A: T band = Qr @ Rh^T  (32 x 1056) -> LDS bf16 ----
    {
        bfrag aQr[2][2];
#pragma unroll
        for (int mt = 0; mt < 2; ++mt)
#pragma unroll
            for (int ks = 0; ks < 2; ++ks)
                aQr[mt][ks] = *(const bfrag*)&sQr[(mt * 16 + l15) * 64 + ks * 32 + l4 * 8];
        int nt = w;
        bfrag cb0, cb1;
        {
            size_t t = (size_t)(tstart + nt * 16 + l15);
            cb0 = *(const bfrag*)&rh[t * 768 + n * 64 + l4 * 8];
            cb1 = *(const bfrag*)&rh[t * 768 + n * 64 + 32 + l4 * 8];
        }
        while (nt < 66) {
            int nn = nt + 4;
            bfrag nb0, nb1;
            if (nn < 66) {
                size_t t = (size_t)(tstart + nn * 16 + l15);
                nb0 = *(const bfrag*)&rh[t * 768 + n * 64 + l4 * 8];
                nb1 = *(const bfrag*)&rh[t * 768 + n * 64 + 32 + l4 * 8];
            }
#pragma unroll
            for (int mt = 0; mt < 2; ++mt) {
                f32x4 acc = {0, 0, 0, 0};
                acc = __builtin_amdgcn_mfma_f32_16x16x32_bf16(aQr[mt][0], cb0, acc, 0, 0, 0);
                acc = __builtin_amdgcn_mfma_f32_16x16x32_bf16(aQr[mt][1], cb1, acc, 0, 0, 0);
#pragma unroll
                for (int rg = 0; rg < 4; ++rg)
                    sT[(mt * 16 + l4 * 4 + rg) * TBW + nt * 16 + l15] = f2bf(acc[rg]);
            }
            cb0 = nb0; cb1 = nb1; nt = nn;
        }
    }
    __syncthreads();

    // ---- Phase B: content scores + epilogue -> sS (bf16, swizzled) ----
    {
        bfrag aQw[2][2];
#pragma unroll
        for (int mt = 0; mt < 2; ++mt)
#pragma unroll
            for (int ks = 0; ks < 2; ++ks)
                aQw[mt][ks] = *(const bfrag*)&sQw[(mt * 16 + l15) * 64 + ks * 32 + l4 * 8];
        int jt = w;
        bfrag cb0, cb1;
        {
            size_t j = (size_t)(b * S_LEN + jt * 16 + l15);
            cb0 = *(const bfrag*)&kh[j * 768 + n * 64 + l4 * 8];
            cb1 = *(const bfrag*)&kh[j * 768 + n * 64 + 32 + l4 * 8];
        }
        while (jt < 64) {
            int jn = jt + 4;
            bfrag nb0, nb1;
            if (jn < 64) {
                size_t j = (size_t)(b * S_LEN + jn * 16 + l15);
                nb0 = *(const bfrag*)&kh[j * 768 + n * 64 + l4 * 8];
                nb1 = *(const bfrag*)&kh[j * 768 + n * 64 + 32 + l4 * 8];
            }
            int j = jt * 16 + l15;
#pragma unroll
            for (int mt = 0; mt < 2; ++mt) {
                f32x4 acc = {0, 0, 0, 0};
                acc = __builtin_amdgcn_mfma_f32_16x16x32_bf16(aQw[mt][0], cb0, acc, 0, 0, 0);
                acc = __builtin_amdgcn_mfma_f32_16x16x32_bf16(aQw[mt][1], cb1, acc, 0, 0, 0);
#pragma unroll
                for (int rg = 0; rg < 4; ++rg) {
                    int il = mt * 16 + l4 * 4 + rg;
                    int i = i0 + il;
                    float pos = bf2f(sT[il * TBW + (31 - il + j)]);
                    float cls = cls_mask[(size_t)i * S_LEN + j];
                    int tt = tt_mat[((size_t)b * S_LEN + i) * S_LEN + j];
                    float ttv = tt ? sSame[il] : sDiff[il];
                    float s = acc[rg] + (pos + ttv) * cls + sAm[j];
                    sS[il * 1024 + (j ^ ((il & 7) << 3))] = f2bf(s);
                }
            }
            cb0 = nb0; cb1 = nb1; jt = jn;
        }
    }
    __syncthreads();

    // ---- softmax over full rows (bf16 in LDS) ----
    {
        int row = tid >> 3, sub = tid & 7;
        ushort_t* rp = &sS[row * 1024];
        int rsw = row & 7;
        float m = -3.0e38f;
        for (int e = 0; e < 16; ++e) {
            int c = (sub + 8 * e) ^ rsw;
            bfrag v = *(const bfrag*)&rp[c * 8];
#pragma unroll
            for (int q = 0; q < 8; ++q) m = fmaxf(m, bf2f((ushort_t)v[q]));
        }
#pragma unroll
        for (int off = 1; off < 8; off <<= 1) m = fmaxf(m, __shfl_xor(m, off));
        float sum = 0.0f;
        for (int e = 0; e < 16; ++e) {
            int c = (sub + 8 * e) ^ rsw;
            bfrag v = *(const bfrag*)&rp[c * 8];
            bfrag st;
#pragma unroll
            for (int q = 0; q < 8; ++q) {
                float ev = __expf(bf2f((ushort_t)v[q]) - m);
                sum += ev;
                st[q] = (short)f2bf(ev);
            }
            *(bfrag*)&rp[c * 8] = st;
        }
#pragma unroll
        for (int off = 1; off < 8; off <<= 1) sum += __shfl_xor(sum, off);
        float inv = 1.0f / sum;
        for (int e = 0; e < 16; ++e) {
            int c = (sub + 8 * e) ^ rsw;
            bfrag v = *(const bfrag*)&rp[c * 8];
            bfrag st;
#pragma unroll
            for (int q = 0; q < 8; ++q) st[q] = (short)f2bf(bf2f((ushort_t)v[q]) * inv);
            *(bfrag*)&rp[c * 8] = st;
        }
    }
    __syncthreads();

    // ---- PV: attn_vec = P @ V ----
    {
        int mt = w & 1, hp = w >> 1;
        int h0 = hp * 32 + l15;
        const ushort_t* v0 = vt + (((size_t)b * NHEAD + n) * 64 + h0) * 1024;
        const ushort_t* v1 = v0 + (size_t)16 * 1024;
        int row = mt * 16 + l15;
        f32x4 acc0 = {0, 0, 0, 0}, acc1 = {0, 0, 0, 0};
        bfrag cv0 = *(const bfrag*)&v0[l4 * 8];
        bfrag cv1 = *(const bfrag*)&v1[l4 * 8];
        for (int ks = 0; ks < 32; ++ks) {
            bfrag nv0, nv1;
            if (ks < 31) {
                nv0 = *(const bfrag*)&v0[(ks + 1) * 32 + l4 * 8];
                nv1 = *(const bfrag*)&v1[(ks + 1) * 32 + l4 * 8];
            }
            bfrag pa = *(const bfrag*)&sS[row * 1024 + (((ks * 4 + l4) ^ (row & 7)) * 8)];
            acc0 = __builtin_amdgcn_mfma_f32_16x16x32_bf16(pa, cv0, acc0, 0, 0, 0);
            acc1 = __builtin_amdgcn_mfma_f32_16x16x32_bf16(pa, cv1, acc1, 0, 0, 0);
            cv0 = nv0; cv1 = nv1;
        }
#pragma unroll
        for (int rg = 0; rg < 4; ++rg) {
            size_t i = (size_t)(b * S_LEN + i0 + mt * 16 + l4 * 4 + rg);
            av[i * 768 + n * 64 + hp * 32 + l15] = f2bf(acc0[rg]);
            av[i * 768 + n * 64 + hp * 32 + 16 + l15] = f2bf(acc1[rg]);
        }
    }
}

// ---------------- residual + layernorm ----------------------------------
__global__ __launch_bounds__(256) void out_ln_kernel(
    const float* __restrict__ query, const float* __restrict__ attn_out,
    const float* __restrict__ g, const float* __restrict__ beta,
    float* __restrict__ out)
{
    __shared__ float sx[768];
    __shared__ float sRed[4];
    int row = blockIdx.x, tid = threadIdx.x;
    int wave = tid >> 6, lane = tid & 63;
    float lsum = 0.0f;
    for (int c = tid; c < 768; c += 256) {
        float x = query[(size_t)row * 768 + c] + attn_out[(size_t)row * 768 + c];
        sx[c] = x;
        lsum += x;
    }
#pragma unroll
    for (int off = 32; off >= 1; off >>= 1) lsum += __shfl_xor(lsum, off);
    if (lane == 0) sRed[wave] = lsum;
    __syncthreads();
    float mu = (sRed[0] + sRed[1] + sRed[2] + sRed[3]) * (1.0f / 768.0f);
    float lvar = 0.0f;
    for (int c = tid; c < 768; c += 256) {
        float d = sx[c] - mu;
        lvar += d * d;
    }
#pragma unroll
    for (int off = 32; off >= 1; off >>= 1) lvar += __shfl_xor(lvar, off);
    __syncthreads();
    if (lane == 0) sRed[wave] = lvar;
    __syncthreads();
    float var = (sRed[0] + sRed[1] + sRed[2] + sRed[3]) * (1.0f / 768.0f);
    float rstd = rsqrtf(var + 1e-9f);
    for (int c = tid; c < 768; c += 256)
        out[(size_t)row * 768 + c] = (sx[c] - mu) * rstd * g[c] + beta[c];
}

extern "C" void kernel_launch(void* const* d_in, const int* in_sizes, int n_in,
                              void* d_out, int out_size, void* d_ws, size_t ws_size,
                              hipStream_t stream)
{
    const float* query = (const float*)d_in[0];
    const float* key   = (const float*)d_in[1];
    const float* value = (const float*)d_in[2];
    const float* r     = (const float*)d_in[3];
    const float* cls_mask = (const float*)d_in[4];
    const int*   tt_mat   = (const int*)d_in[5];
    const int*   amask    = (const int*)d_in[6];
    const float* wq  = (const float*)d_in[7];
    const float* wk  = (const float*)d_in[8];
    const float* bk  = (const float*)d_in[9];
    const float* wv  = (const float*)d_in[10];
    const float* bv  = (const float*)d_in[11];
    const float* rwb = (const float*)d_in[12];
    const float* rrb = (const float*)d_in[13];
    const float* rsb = (const float*)d_in[14];
    const float* rk  = (const float*)d_in[15];
    const float* seg = (const float*)d_in[16];
    const float* wo  = (const float*)d_in[17];
    const float* bo  = (const float*)d_in[18];
    const float* lng = (const float*)d_in[19];
    const float* lnb = (const float*)d_in[20];
    float* out = (float*)d_out;

    char* W = (char*)d_ws;
    float*    qh  = (float*)W;                       // 6291456 B
    ushort_t* kh  = (ushort_t*)(W + 6291456);        // 3145728
    ushort_t* vt  = (ushort_t*)(W + 9437184);        // 3145728
    ushort_t* rh  = (ushort_t*)(W + 12582912);       // 3170304 (2064 rows)
    ushort_t* av  = (ushort_t*)(W + 15753216);       // 3145728
    ushort_t* qx  = (ushort_t*)(W + 18898944);       // 3145728
    ushort_t* kx  = (ushort_t*)(W + 22044672);       // 3145728
    ushort_t* vx  = (ushort_t*)(W + 25190400);       // 3145728
    ushort_t* rx  = (ushort_t*)(W + 28336128);       // 3145728
    ushort_t* wqT = (ushort_t*)(W + 31481856);       // 1179648
    ushort_t* wkT = (ushort_t*)(W + 32661504);
    ushort_t* wvT = (ushort_t*)(W + 33841152);
    ushort_t* rkT = (ushort_t*)(W + 35020800);
    ushort_t* woT = (ushort_t*)(W + 36200448);       // ends 37380096
    float* attn_out = (float*)(W + 18898944);        // aliases qx..kx (safe: used after)

    const int NEL = 2048 * 768;
    hipLaunchKernelGGL(cvt_bf16, dim3(NEL / 1024), dim3(256), 0, stream, query, qx, NEL);
    hipLaunchKernelGGL(cvt_bf16, dim3(NEL / 1024), dim3(256), 0, stream, key, kx, NEL);
    hipLaunchKernelGGL(cvt_bf16, dim3(NEL / 1024), dim3(256), 0, stream, value, vx, NEL);
    hipLaunchKernelGGL(cvt_bf16, dim3(NEL / 1024), dim3(256), 0, stream, r, rx, NEL);

    hipLaunchKernelGGL(tcvt, dim3(12, 12), dim3(256), 0, stream, wq, wqT);
    hipLaunchKernelGGL(tcvt, dim3(12, 12), dim3(256), 0, stream, wk, wkT);
    hipLaunchKernelGGL(tcvt, dim3(12, 12), dim3(256), 0, stream, wv, wvT);
    hipLaunchKernelGGL(tcvt, dim3(12, 12), dim3(256), 0, stream, rk, rkT);
    hipLaunchKernelGGL(tcvt, dim3(12, 12), dim3(256), 0, stream, wo, woT);

    dim3 gg(32, 12);
    hipLaunchKernelGGL(gemm_mfma, gg, dim3(256), 0, stream, qx, wqT, (const float*)nullptr, qh, (ushort_t*)nullptr, SCALE, 0);
    hipLaunchKernelGGL(gemm_mfma, gg, dim3(256), 0, stream, kx, wkT, bk, (float*)nullptr, kh, 1.0f, 1);
    hipLaunchKernelGGL(gemm_mfma, gg, dim3(256), 0, stream, vx, wvT, bv, (float*)nullptr, vt, 1.0f, 2);
    hipLaunchKernelGGL(gemm_mfma, gg, dim3(256), 0, stream, rx, rkT, (const float*)nullptr, (float*)nullptr, rh, 1.0f, 1);

    hipLaunchKernelGGL(attn_mfma, dim3(32, 12, 2), dim3(256), 0, stream,
                       qh, kh, vt, rh, rwb, rrb, rsb, seg, cls_mask, tt_mat, amask, av);

    hipLaunchKernelGGL(gemm_mfma, gg, dim3(256), 0, stream, av, woT, bo, attn_out, (ushort_t*)nullptr, 1.0f, 0);
    hipLaunchKernelGGL(out_ln_kernel, dim3(2048), dim3(256), 0, stream, query, attn_out, lng, lnb, out);
}

// Round 3
// 157.792 us; speedup vs baseline: 4.3111x; 1.4903x over previous
//
#include <hip/hip_runtime.h>

#define S_LEN 1024
#define NHEAD 12
#define SCALE 0.125f
#define INF_ 1000000.0f

typedef __attribute__((ext_vector_type(8))) short bfrag;
typedef __attribute__((ext_vector_type(4))) float f32x4;
typedef unsigned short ushort_t;
typedef unsigned int uint_t;
typedef unsigned long long u64_t;

__device__ inline ushort_t f2bf(float f) {
    union { float f; uint_t u; } v; v.f = f;
    uint_t u = v.u;
    return (ushort_t)((u + 0x7fffu + ((u >> 16) & 1u)) >> 16);
}
__device__ inline float bf2f(ushort_t h) {
    union { uint_t u; float f; } v; v.u = ((uint_t)h) << 16;
    return v.f;
}

// ---------------- mask pre-pack ------------------------------------------
// grid (1024, 2), block 256. cls -> bf16 (b==0 only); tt -> u64 bitmask.
__global__ __launch_bounds__(256) void pack_masks(
    const float* __restrict__ cls, const int* __restrict__ tt,
    ushort_t* __restrict__ clsb, u64_t* __restrict__ ttb)
{
    int i = blockIdx.x, b = blockIdx.y, tid = threadIdx.x;
    int wave = tid >> 6, lane = tid & 63;
    if (b == 0) {
        for (int j = tid; j < 1024; j += 256)
            clsb[(size_t)i * 1024 + j] = f2bf(cls[(size_t)i * 1024 + j]);
    }
#pragma unroll
    for (int l = 0; l < 4; ++l) {
        int j = l * 256 + tid;
        int v = tt[((size_t)b * 1024 + i) * 1024 + j];
        u64_t m = __ballot(v != 0);
        if (lane == 0) ttb[((size_t)b * 1024 + i) * 16 + l * 4 + wave] = m;
    }
}

// ---------------- weight transpose+convert (batched) ---------------------
struct TJobs { const float* src[5]; ushort_t* dst[5]; };
__global__ __launch_bounds__(256) void tcvt_multi(TJobs jobs) {
    __shared__ float tile[64][65];
    const float* src = jobs.src[blockIdx.z];
    ushort_t* dst = jobs.dst[blockIdx.z];
    int bx = blockIdx.x * 64, by = blockIdx.y * 64;
    for (int e = threadIdx.x; e < 4096; e += 256) {
        int r = e >> 6, c = e & 63;
        tile[r][c] = src[(size_t)(by + r) * 768 + bx + c];
    }
    __syncthreads();
    for (int e = threadIdx.x; e < 4096; e += 256) {
        int r = e >> 6, c = e & 63;
        dst[(size_t)(bx + r) * 768 + by + c] = f2bf(tile[c][r]);
    }
}

// ---------------- batched bf16 MFMA GEMM (M=2048,N=768,K=768) ------------
// A: f32 (Af) converted in staging, or bf16 (Ah). BT bf16 [n][k].
// mode 0: Cf[row*768+col] = acc*scale + bias
// mode 1: Ch[row*768+col] = bf16(acc + bias)
// mode 2: Ch[((row>>10)*768+col)*1024 + (row&1023)] = bf16(acc + bias)
struct GemmJob {
    const float* Af; const ushort_t* Ah; const ushort_t* BT;
    const float* bias; float* Cf; ushort_t* Ch; float scale; int mode;
};
struct GemmJobs4 { GemmJob j[4]; };

__global__ __launch_bounds__(256) void gemm_batch(GemmJobs4 jobs) {
    GemmJob jb = jobs.j[blockIdx.z];
    __shared__ __align__(16) ushort_t As[64 * 40];
    __shared__ __align__(16) ushort_t Bs[64 * 40];
    int tid = threadIdx.x;
    int w = tid >> 6, lane = tid & 63, l15 = lane & 15, l4 = lane >> 4;
    int rowBase = blockIdx.x * 64, colBase = blockIdx.y * 64;
    int wm = w >> 1, wn = w & 1;
    f32x4 acc[2][2] = {{{0,0,0,0},{0,0,0,0}},{{0,0,0,0},{0,0,0,0}}};
    int srow = tid >> 2, schunk = (tid & 3) * 8;
    for (int k0 = 0; k0 < 768; k0 += 32) {
        __syncthreads();
        if (jb.Ah) {
            *(uint4*)&As[srow * 40 + schunk] =
                *(const uint4*)&jb.Ah[(size_t)(rowBase + srow) * 768 + k0 + schunk];
        } else {
            const float* ap = &jb.Af[(size_t)(rowBase + srow) * 768 + k0 + schunk];
            float4 v0 = *(const float4*)ap, v1 = *(const float4*)(ap + 4);
            ushort_t tmp[8] = {f2bf(v0.x), f2bf(v0.y), f2bf(v0.z), f2bf(v0.w),
                               f2bf(v1.x), f2bf(v1.y), f2bf(v1.z), f2bf(v1.w)};
            *(uint4*)&As[srow * 40 + schunk] = *(const uint4*)tmp;
        }
        *(uint4*)&Bs[srow * 40 + schunk] =
            *(const uint4*)&jb.BT[(size_t)(colBase + srow) * 768 + k0 + schunk];
        __syncthreads();
        bfrag bfr[2];
#pragma unroll
        for (int nf = 0; nf < 2; ++nf)
            bfr[nf] = *(const bfrag*)&Bs[(wn * 32 + nf * 16 + l15) * 40 + l4 * 8];
#pragma unroll
        for (int mf = 0; mf < 2; ++mf) {
            bfrag af = *(const bfrag*)&As[(wm * 32 + mf * 16 + l15) * 40 + l4 * 8];
#pragma unroll
            for (int nf = 0; nf < 2; ++nf)
                acc[mf][nf] = __builtin_amdgcn_mfma_f32_16x16x32_bf16(af, bfr[nf], acc[mf][nf], 0, 0, 0);
        }
    }
#pragma unroll
    for (int mf = 0; mf < 2; ++mf)
#pragma unroll
        for (int nf = 0; nf < 2; ++nf)
#pragma unroll
            for (int rg = 0; rg < 4; ++rg) {
                int row = rowBase + wm * 32 + mf * 16 + l4 * 4 + rg;
                int col = colBase + wn * 32 + nf * 16 + l15;
                float v = acc[mf][nf][rg] * jb.scale + (jb.bias ? jb.bias[col] : 0.0f);
                if (jb.mode == 0) jb.Cf[(size_t)row * 768 + col] = v;
                else if (jb.mode == 1) jb.Ch[(size_t)row * 768 + col] = f2bf(v);
                else jb.Ch[((size_t)(row >> 10) * 768 + col) * 1024 + (row & 1023)] = f2bf(v);
            }
}

// ---------------- fused attention (MFMA, band-scatter, 78KB LDS) ---------
// grid (32, 12, 2), block 256 (4 waves). 32 q-rows per block.
__global__ __launch_bounds__(256) void attn_mfma(
    const float* __restrict__ qh,      // (B*S,768) f32, pre-scaled
    const ushort_t* __restrict__ kh,   // (B*S,768) bf16
    const ushort_t* __restrict__ vt,   // (B,768,S) bf16
    const ushort_t* __restrict__ rh,   // (2064,768) bf16 (rows>=2048 unused)
    const float* __restrict__ rwb, const float* __restrict__ rrb,
    const float* __restrict__ rsb, const float* __restrict__ seg,
    const ushort_t* __restrict__ clsb, // (S,S) bf16
    const u64_t* __restrict__ ttb,     // (B,S,16) bitmask
    const int* __restrict__ amask,     // (B,S)
    ushort_t* __restrict__ av)         // (B*S,768) bf16
{
    __shared__ __align__(16) ushort_t sQw[32 * 64];
    __shared__ __align__(16) ushort_t sQr[32 * 64];
    __shared__ __align__(16) ushort_t sS[32 * 1024];
    __shared__ ushort_t sAm[1024];
    __shared__ u64_t sTT[32 * 16];
    __shared__ float sDiff[32], sSame[32];

    const int tid = threadIdx.x;
    const int w = tid >> 6, lane = tid & 63;
    const int l15 = lane & 15, l4 = lane >> 4;
    const int i0 = blockIdx.x * 32;
    const int n = blockIdx.y;
    const int b = blockIdx.z;

    // ---- stage Q variants, seg dots, amask, tt bits ----
    {
        const float* qbase = qh + ((size_t)(b * S_LEN + i0)) * 768 + n * 64;
        float s0 = seg[n * 64 + lane], s1 = seg[768 + n * 64 + lane];
        float bw = rwb[n * 64 + lane] * SCALE;
        float br = rrb[n * 64 + lane] * SCALE;
        float bs = rsb[n * 64 + lane] * SCALE;
#pragma unroll
        for (int l = 0; l < 8; ++l) {
            int r = w + 4 * l;
            float qv = qbase[(size_t)r * 768 + lane];
            sQw[r * 64 + lane] = f2bf(qv + bw);
            sQr[r * 64 + lane] = f2bf(qv + br);
            float qs = qv + bs;
            float d = qs * s0, sm = qs * s1;
#pragma unroll
            for (int off = 32; off >= 1; off >>= 1) {
                d += __shfl_xor(d, off);
                sm += __shfl_xor(sm, off);
            }
            if (lane == 0) { sDiff[r] = d; sSame[r] = sm; }
        }
        for (int j = tid; j < 1024; j += 256)
            sAm[j] = f2bf(-INF_ * (1.0f - (float)amask[b * S_LEN + j]));
        for (int e = tid; e < 512; e += 256)
            sTT[e] = ttb[((size_t)b * 1024 + i0 + (e >> 4)) * 16 + (e & 15)];
    }
    __syncthreads();

    const int tstart = 993 - i0;  // S - i0 - 31

    // ---- Phase A: pos band = Qr @ Rh^T, scattered directly into sS ----
    {
        bfrag aQr[2][2];
#pragma unroll
        for (int mt = 0; mt < 2; ++mt)
#pragma unroll
            for (int ks = 0; ks < 2; ++ks)
                aQr[mt][ks] = *(const bfrag*)&sQr[(mt * 16 + l15) * 64 + ks * 32 + l4 * 8];
        for (int nt = w; nt < 66; nt += 4) {
            size_t t = (size_t)(tstart + nt * 16 + l15);
            const ushort_t* rp = &rh[t * 768 + n * 64 + l4 * 8];
            bfrag b0 = *(const bfrag*)rp;
            bfrag b1 = *(const bfrag*)(rp + 32);
            int tp = nt * 16 + l15;
#pragma unroll
            for (int mt = 0; mt < 2; ++mt) {
                f32x4 acc = {0, 0, 0, 0};
                acc = __builtin_amdgcn_mfma_f32_16x16x32_bf16(aQr[mt][0], b0, acc, 0, 0, 0);
                acc = __builtin_amdgcn_mfma_f32_16x16x32_bf16(aQr[mt][1], b1, acc, 0, 0, 0);
#pragma unroll
                for (int rg = 0; rg < 4; ++rg) {
                    int il = mt * 16 + l4 * 4 + rg;
                    int j = tp - 31 + il;
                    if ((unsigned)j < 1024u)
                        sS[il * 1024 + (j ^ ((il & 7) << 3))] = f2bf(acc[rg]);
                }
            }
        }
    }
    __syncthreads();

    // ---- Phase B: content MFMA + epilogue (read pos, add, write back) ----
    {
        bfrag aQw[2][2];
#pragma unroll
        for (int mt = 0; mt < 2; ++mt)
#pragma unroll
            for (int ks = 0; ks < 2; ++ks)
                aQw[mt][ks] = *(const bfrag*)&sQw[(mt * 16 + l15) * 64 + ks * 32 + l4 * 8];
        for (int jt = w; jt < 64; jt += 4) {
            size_t jrow = (size_t)(b * S_LEN + jt * 16 + l15);
            const ushort_t* kp = &kh[jrow * 768 + n * 64 + l4 * 8];
            bfrag b0 = *(const bfrag*)kp;
            bfrag b1 = *(const bfrag*)(kp + 32);
            int j = jt * 16 + l15;
            float am = bf2f(sAm[j]);
#pragma unroll
            for (int mt = 0; mt < 2; ++mt) {
                f32x4 acc = {0, 0, 0, 0};
                acc = __builtin_amdgcn_mfma_f32_16x16x32_bf16(aQw[mt][0], b0, acc, 0, 0, 0);
                acc = __builtin_amdgcn_mfma_f32_16x16x32_bf16(aQw[mt][1], b1, acc, 0, 0, 0);
#pragma unroll
                for (int rg = 0; rg < 4; ++rg) {
                    int il = mt * 16 + l4 * 4 + rg;
                    int i = i0 + il;
                    int sidx = il * 1024 + (j ^ ((il & 7) << 3));
                    float pos = bf2f(sS[sidx]);
                    float cls = bf2f(clsb[(size_t)i * 1024 + j]);
                    u64_t tw = sTT[il * 16 + (j >> 6)];
                    float ttv = ((tw >> (j & 63)) & 1ull) ? sSame[il] : sDiff[il];
                    float s = acc[rg] + (pos + ttv) * cls + am;
                    sS[sidx] = f2bf(s);
                }
            }
        }
    }
    __syncthreads();

    // ---- softmax per row (bf16 in LDS, swizzled) ----
    {
        int row = tid >> 3, sub = tid & 7;
        ushort_t* rp = &sS[row * 1024];
        int rsw = row & 7;
        float m = -3.0e38f;
        for (int e = 0; e < 16; ++e) {
            int c = (sub + 8 * e) ^ rsw;
            bfrag v = *(const bfrag*)&rp[c * 8];
#pragma unroll
            for (int q = 0; q < 8; ++q) m = fmaxf(m, bf2f((ushort_t)v[q]));
        }
#pragma unroll
        for (int off = 1; off < 8; off <<= 1) m = fmaxf(m, __shfl_xor(m, off));
        float sum = 0.0f;
        for (int e = 0; e < 16; ++e) {
            int c = (sub + 8 * e) ^ rsw;
            bfrag v = *(const bfrag*)&rp[c * 8];
            bfrag st;
#pragma unroll
            for (int q = 0; q < 8; ++q) {
                float ev = __expf(bf2f((ushort_t)v[q]) - m);
                sum += ev;
                st[q] = (short)f2bf(ev);
            }
            *(bfrag*)&rp[c * 8] = st;
        }
#pragma unroll
        for (int off = 1; off < 8; off <<= 1) sum += __shfl_xor(sum, off);
        float inv = 1.0f / sum;
        for (int e = 0; e < 16; ++e) {
            int c = (sub + 8 * e) ^ rsw;
            bfrag v = *(const bfrag*)&rp[c * 8];
            bfrag st;
#pragma unroll
            for (int q = 0; q < 8; ++q) st[q] = (short)f2bf(bf2f((ushort_t)v[q]) * inv);
            *(bfrag*)&rp[c * 8] = st;
        }
    }
    __syncthreads();

    // ---- PV: attn_vec = P @ V ----
    {
        int mt = w & 1, hp = w >> 1;
        int h0 = hp * 32 + l15;
        const ushort_t* v0 = vt + (((size_t)b * NHEAD + n) * 64 + h0) * 1024;
        const ushort_t* v1 = v0 + (size_t)16 * 1024;
        int row = mt * 16 + l15;
        f32x4 acc0 = {0, 0, 0, 0}, acc1 = {0, 0, 0, 0};
        bfrag cv0 = *(const bfrag*)&v0[l4 * 8];
        bfrag cv1 = *(const bfrag*)&v1[l4 * 8];
        for (int ks = 0; ks < 32; ++ks) {
            bfrag nv0, nv1;
            if (ks < 31) {
                nv0 = *(const bfrag*)&v0[(ks + 1) * 32 + l4 * 8];
                nv1 = *(const bfrag*)&v1[(ks + 1) * 32 + l4 * 8];
            }
            bfrag pa = *(const bfrag*)&sS[row * 1024 + (((ks * 4 + l4) ^ (row & 7)) * 8)];
            acc0 = __builtin_amdgcn_mfma_f32_16x16x32_bf16(pa, cv0, acc0, 0, 0, 0);
            acc1 = __builtin_amdgcn_mfma_f32_16x16x32_bf16(pa, cv1, acc1, 0, 0, 0);
            cv0 = nv0; cv1 = nv1;
        }
#pragma unroll
        for (int rg = 0; rg < 4; ++rg) {
            size_t i = (size_t)(b * S_LEN + i0 + mt * 16 + l4 * 4 + rg);
            av[i * 768 + n * 64 + hp * 32 + l15] = f2bf(acc0[rg]);
            av[i * 768 + n * 64 + hp * 32 + 16 + l15] = f2bf(acc1[rg]);
        }
    }
}

// ---------------- residual + layernorm ----------------------------------
__global__ __launch_bounds__(256) void out_ln_kernel(
    const float* __restrict__ query, const float* __restrict__ attn_out,
    const float* __restrict__ g, const float* __restrict__ beta,
    float* __restrict__ out)
{
    __shared__ float sx[768];
    __shared__ float sRed[4];
    int row = blockIdx.x, tid = threadIdx.x;
    int wave = tid >> 6, lane = tid & 63;
    float lsum = 0.0f;
    for (int c = tid; c < 768; c += 256) {
        float x = query[(size_t)row * 768 + c] + attn_out[(size_t)row * 768 + c];
        sx[c] = x;
        lsum += x;
    }
#pragma unroll
    for (int off = 32; off >= 1; off >>= 1) lsum += __shfl_xor(lsum, off);
    if (lane == 0) sRed[wave] = lsum;
    __syncthreads();
    float mu = (sRed[0] + sRed[1] + sRed[2] + sRed[3]) * (1.0f / 768.0f);
    float lvar = 0.0f;
    for (int c = tid; c < 768; c += 256) {
        float d = sx[c] - mu;
        lvar += d * d;
    }
#pragma unroll
    for (int off = 32; off >= 1; off >>= 1) lvar += __shfl_xor(lvar, off);
    __syncthreads();
    if (lane == 0) sRed[wave] = lvar;
    __syncthreads();
    float var = (sRed[0] + sRed[1] + sRed[2] + sRed[3]) * (1.0f / 768.0f);
    float rstd = rsqrtf(var + 1e-9f);
    for (int c = tid; c < 768; c += 256)
        out[(size_t)row * 768 + c] = (sx[c] - mu) * rstd * g[c] + beta[c];
}

extern "C" void kernel_launch(void* const* d_in, const int* in_sizes, int n_in,
                              void* d_out, int out_size, void* d_ws, size_t ws_size,
                              hipStream_t stream)
{
    const float* query = (const float*)d_in[0];
    const float* key   = (const float*)d_in[1];
    const float* value = (const float*)d_in[2];
    const float* r     = (const float*)d_in[3];
    const float* cls_mask = (const float*)d_in[4];
    const int*   tt_mat   = (const int*)d_in[5];
    const int*   amask    = (const int*)d_in[6];
    const float* wq  = (const float*)d_in[7];
    const float* wk  = (const float*)d_in[8];
    const float* bk  = (const float*)d_in[9];
    const float* wv  = (const float*)d_in[10];
    const float* bv  = (const float*)d_in[11];
    const float* rwb = (const float*)d_in[12];
    const float* rrb = (const float*)d_in[13];
    const float* rsb = (const float*)d_in[14];
    const float* rk  = (const float*)d_in[15];
    const float* seg = (const float*)d_in[16];
    const float* wo  = (const float*)d_in[17];
    const float* bo  = (const float*)d_in[18];
    const float* lng = (const float*)d_in[19];
    const float* lnb = (const float*)d_in[20];
    float* out = (float*)d_out;

    char* W = (char*)d_ws;
    float*    qh  = (float*)W;                       // 0       (+6291456)
    ushort_t* kh  = (ushort_t*)(W + 6291456);        // +3145728
    ushort_t* vt  = (ushort_t*)(W + 9437184);        // +3145728
    ushort_t* rh  = (ushort_t*)(W + 12582912);       // +3170304 (2064 rows)
    ushort_t* av  = (ushort_t*)(W + 15753216);       // +3145728
    ushort_t* wqT = (ushort_t*)(W + 18898944);       // +1179648
    ushort_t* wkT = (ushort_t*)(W + 20078592);
    ushort_t* wvT = (ushort_t*)(W + 21258240);
    ushort_t* rkT = (ushort_t*)(W + 22437888);
    ushort_t* woT = (ushort_t*)(W + 23617536);       // ends 24797184
    ushort_t* clsb = (ushort_t*)(W + 24797184);      // +2097152
    u64_t*    ttb  = (u64_t*)(W + 26894336);         // +262144
    float* attn_out = (float*)(W + 27156480);        // +6291456 -> 33447936

    hipLaunchKernelGGL(pack_masks, dim3(1024, 2), dim3(256), 0, stream,
                       cls_mask, tt_mat, clsb, ttb);

    TJobs tj;
    tj.src[0] = wq; tj.dst[0] = wqT;
    tj.src[1] = wk; tj.dst[1] = wkT;
    tj.src[2] = wv; tj.dst[2] = wvT;
    tj.src[3] = rk; tj.dst[3] = rkT;
    tj.src[4] = wo; tj.dst[4] = woT;
    hipLaunchKernelGGL(tcvt_multi, dim3(12, 12, 5), dim3(256), 0, stream, tj);

    GemmJobs4 pj;
    pj.j[0] = {query, nullptr, wqT, nullptr, qh, nullptr, SCALE, 0};
    pj.j[1] = {key,   nullptr, wkT, bk, nullptr, kh, 1.0f, 1};
    pj.j[2] = {value, nullptr, wvT, bv, nullptr, vt, 1.0f, 2};
    pj.j[3] = {r,     nullptr, rkT, nullptr, nullptr, rh, 1.0f, 1};
    hipLaunchKernelGGL(gemm_batch, dim3(32, 12, 4), dim3(256), 0, stream, pj);

    hipLaunchKernelGGL(attn_mfma, dim3(32, 12, 2), dim3(256), 0, stream,
                       qh, kh, vt, rh, rwb, rrb, rsb, seg, clsb, ttb, amask, av);

    GemmJobs4 oj;
    oj.j[0] = {nullptr, av, woT, bo, attn_out, nullptr, 1.0f, 0};
    oj.j[1] = oj.j[0]; oj.j[2] = oj.j[0]; oj.j[3] = oj.j[0];
    hipLaunchKernelGGL(gemm_batch, dim3(32, 12, 1), dim3(256), 0, stream, oj);

    hipLaunchKernelGGL(out_ln_kernel, dim3(2048), dim3(256), 0, stream,
                       query, attn_out, lng, lnb, out);
}

// Round 4
// 146.637 us; speedup vs baseline: 4.6391x; 1.0761x over previous
//
#include <hip/hip_runtime.h>

#define S_LEN 1024
#define NHEAD 12
#define SCALE 0.125f
#define INF_ 1000000.0f

typedef __attribute__((ext_vector_type(8))) short bfrag;
typedef __attribute__((ext_vector_type(4))) float f32x4;
typedef unsigned short ushort_t;
typedef unsigned int uint_t;
typedef unsigned long long u64_t;

__device__ inline ushort_t f2bf(float f) {
    union { float f; uint_t u; } v; v.f = f;
    uint_t u = v.u;
    return (ushort_t)((u + 0x7fffu + ((u >> 16) & 1u)) >> 16);
}
__device__ inline float bf2f(ushort_t h) {
    union { uint_t u; float f; } v; v.u = ((uint_t)h) << 16;
    return v.f;
}

// ---------------- mask pre-pack ------------------------------------------
__global__ __launch_bounds__(256) void pack_masks(
    const float* __restrict__ cls, const int* __restrict__ tt,
    ushort_t* __restrict__ clsb, u64_t* __restrict__ ttb)
{
    int i = blockIdx.x, b = blockIdx.y, tid = threadIdx.x;
    int wave = tid >> 6, lane = tid & 63;
    if (b == 0) {
        for (int j = tid; j < 1024; j += 256)
            clsb[(size_t)i * 1024 + j] = f2bf(cls[(size_t)i * 1024 + j]);
    }
#pragma unroll
    for (int l = 0; l < 4; ++l) {
        int j = l * 256 + tid;
        int v = tt[((size_t)b * 1024 + i) * 1024 + j];
        u64_t m = __ballot(v != 0);
        if (lane == 0) ttb[((size_t)b * 1024 + i) * 16 + l * 4 + wave] = m;
    }
}

// ---------------- weight transpose+convert (batched) ---------------------
struct TJobs { const float* src[5]; ushort_t* dst[5]; };
__global__ __launch_bounds__(256) void tcvt_multi(TJobs jobs) {
    __shared__ float tile[64][65];
    const float* src = jobs.src[blockIdx.z];
    ushort_t* dst = jobs.dst[blockIdx.z];
    int bx = blockIdx.x * 64, by = blockIdx.y * 64;
    for (int e = threadIdx.x; e < 4096; e += 256) {
        int r = e >> 6, c = e & 63;
        tile[r][c] = src[(size_t)(by + r) * 768 + bx + c];
    }
    __syncthreads();
    for (int e = threadIdx.x; e < 4096; e += 256) {
        int r = e >> 6, c = e & 63;
        dst[(size_t)(bx + r) * 768 + by + c] = f2bf(tile[c][r]);
    }
}

// ---------------- batched bf16 MFMA GEMM (register-prefetched) -----------
struct GemmJob {
    const float* Af; const ushort_t* Ah; const ushort_t* BT;
    const float* bias; float* Cf; ushort_t* Ch; float scale; int mode;
};
struct GemmJobs4 { GemmJob j[4]; };

__global__ __launch_bounds__(256) void gemm_batch(GemmJobs4 jobs) {
    GemmJob jb = jobs.j[blockIdx.z];
    __shared__ __align__(16) ushort_t As[64 * 40];
    __shared__ __align__(16) ushort_t Bs[64 * 40];
    int tid = threadIdx.x;
    int w = tid >> 6, lane = tid & 63, l15 = lane & 15, l4 = lane >> 4;
    int rowBase = blockIdx.x * 64, colBase = blockIdx.y * 64;
    int wm = w >> 1, wn = w & 1;
    f32x4 acc[2][2] = {{{0,0,0,0},{0,0,0,0}},{{0,0,0,0},{0,0,0,0}}};
    int srow = tid >> 2, schunk = (tid & 3) * 8;
    const bool cvt = (jb.Ah == nullptr);

    float4 fa0, fa1; uint4 ra, rb;
    if (cvt) {
        const float* ap = &jb.Af[(size_t)(rowBase + srow) * 768 + schunk];
        fa0 = *(const float4*)ap; fa1 = *(const float4*)(ap + 4);
    } else {
        ra = *(const uint4*)&jb.Ah[(size_t)(rowBase + srow) * 768 + schunk];
    }
    rb = *(const uint4*)&jb.BT[(size_t)(colBase + srow) * 768 + schunk];

    for (int k0 = 0; k0 < 768; k0 += 32) {
        __syncthreads();
        if (cvt) {
            ushort_t tmp[8] = {f2bf(fa0.x), f2bf(fa0.y), f2bf(fa0.z), f2bf(fa0.w),
                               f2bf(fa1.x), f2bf(fa1.y), f2bf(fa1.z), f2bf(fa1.w)};
            *(uint4*)&As[srow * 40 + schunk] = *(const uint4*)tmp;
        } else {
            *(uint4*)&As[srow * 40 + schunk] = ra;
        }
        *(uint4*)&Bs[srow * 40 + schunk] = rb;
        __syncthreads();
        int kn = k0 + 32;
        if (kn < 768) {
            if (cvt) {
                const float* ap = &jb.Af[(size_t)(rowBase + srow) * 768 + kn + schunk];
                fa0 = *(const float4*)ap; fa1 = *(const float4*)(ap + 4);
            } else {
                ra = *(const uint4*)&jb.Ah[(size_t)(rowBase + srow) * 768 + kn + schunk];
            }
            rb = *(const uint4*)&jb.BT[(size_t)(colBase + srow) * 768 + kn + schunk];
        }
        bfrag bfr[2];
#pragma unroll
        for (int nf = 0; nf < 2; ++nf)
            bfr[nf] = *(const bfrag*)&Bs[(wn * 32 + nf * 16 + l15) * 40 + l4 * 8];
#pragma unroll
        for (int mf = 0; mf < 2; ++mf) {
            bfrag af = *(const bfrag*)&As[(wm * 32 + mf * 16 + l15) * 40 + l4 * 8];
#pragma unroll
            for (int nf = 0; nf < 2; ++nf)
                acc[mf][nf] = __builtin_amdgcn_mfma_f32_16x16x32_bf16(af, bfr[nf], acc[mf][nf], 0, 0, 0);
        }
    }
#pragma unroll
    for (int mf = 0; mf < 2; ++mf)
#pragma unroll
        for (int nf = 0; nf < 2; ++nf)
#pragma unroll
            for (int rg = 0; rg < 4; ++rg) {
                int row = rowBase + wm * 32 + mf * 16 + l4 * 4 + rg;
                int col = colBase + wn * 32 + nf * 16 + l15;
                float v = acc[mf][nf][rg] * jb.scale + (jb.bias ? jb.bias[col] : 0.0f);
                if (jb.mode == 0) jb.Cf[(size_t)row * 768 + col] = v;
                else if (jb.mode == 1) jb.Ch[(size_t)row * 768 + col] = f2bf(v);
                else jb.Ch[((size_t)(row >> 10) * 768 + col) * 1024 + (row & 1023)] = f2bf(v);
            }
}

// ---------------- fused attention: 16 q-rows/block, ~41KB LDS ------------
// grid (64, 12, 2), block 256 (4 waves).
__global__ __launch_bounds__(256) void attn_mfma(
    const float* __restrict__ qh,      // (B*S,768) f32, pre-scaled
    const ushort_t* __restrict__ kh,   // (B*S,768) bf16
    const ushort_t* __restrict__ vt,   // (B,768,S) bf16
    const ushort_t* __restrict__ rh,   // (2064,768) bf16
    const float* __restrict__ rwb, const float* __restrict__ rrb,
    const float* __restrict__ rsb, const float* __restrict__ seg,
    const ushort_t* __restrict__ clsb, // (S,S) bf16
    const u64_t* __restrict__ ttb,     // (B,S,16) bitmask
    const int* __restrict__ amask,     // (B,S)
    ushort_t* __restrict__ av)         // (B*S,768) bf16
{
    __shared__ __align__(16) ushort_t sQw[16 * 64];
    __shared__ __align__(16) ushort_t sQr[16 * 64];
    __shared__ __align__(16) ushort_t sS[16 * 1024];
    __shared__ ushort_t sAm[1024];
    __shared__ u64_t sTT[16 * 16];
    __shared__ float sDiff[16], sSame[16];

    const int tid = threadIdx.x;
    const int w = tid >> 6, lane = tid & 63;
    const int l15 = lane & 15, l4 = lane >> 4;
    const int i0 = blockIdx.x * 16;
    const int n = blockIdx.y;
    const int b = blockIdx.z;

    // ---- stage Q variants, seg dots, amask, tt bits ----
    {
        const float* qbase = qh + ((size_t)(b * S_LEN + i0)) * 768 + n * 64;
        float s0 = seg[n * 64 + lane], s1 = seg[768 + n * 64 + lane];
        float bw = rwb[n * 64 + lane] * SCALE;
        float br = rrb[n * 64 + lane] * SCALE;
        float bs = rsb[n * 64 + lane] * SCALE;
#pragma unroll
        for (int l = 0; l < 4; ++l) {
            int r = w + 4 * l;
            float qv = qbase[(size_t)r * 768 + lane];
            sQw[r * 64 + lane] = f2bf(qv + bw);
            sQr[r * 64 + lane] = f2bf(qv + br);
            float qs = qv + bs;
            float d = qs * s0, sm = qs * s1;
#pragma unroll
            for (int off = 32; off >= 1; off >>= 1) {
                d += __shfl_xor(d, off);
                sm += __shfl_xor(sm, off);
            }
            if (lane == 0) { sDiff[r] = d; sSame[r] = sm; }
        }
        for (int j = tid; j < 1024; j += 256)
            sAm[j] = f2bf(-INF_ * (1.0f - (float)amask[b * S_LEN + j]));
        if (tid < 256) {
            int e = tid;
            sTT[e] = ttb[((size_t)b * 1024 + i0 + (e >> 4)) * 16 + (e & 15)];
        }
    }
    __syncthreads();

    const int tstart = 1009 - i0;  // S - i0 - 15

    // ---- Phase A: pos band = Qr @ Rh^T, scattered into sS (prefetched) --
    {
        bfrag aQr[2];
#pragma unroll
        for (int ks = 0; ks < 2; ++ks)
            aQr[ks] = *(const bfrag*)&sQr[l15 * 64 + ks * 32 + l4 * 8];
        int nt = w;
        bfrag cb0, cb1;
        {
            size_t t = (size_t)(tstart + nt * 16 + l15);
            const ushort_t* rp = &rh[t * 768 + n * 64 + l4 * 8];
            cb0 = *(const bfrag*)rp; cb1 = *(const bfrag*)(rp + 32);
        }
        while (nt < 65) {
            int nn = nt + 4;
            bfrag nb0, nb1;
            if (nn < 65) {
                size_t t = (size_t)(tstart + nn * 16 + l15);
                const ushort_t* rp = &rh[t * 768 + n * 64 + l4 * 8];
                nb0 = *(const bfrag*)rp; nb1 = *(const bfrag*)(rp + 32);
            }
            f32x4 acc = {0, 0, 0, 0};
            acc = __builtin_amdgcn_mfma_f32_16x16x32_bf16(aQr[0], cb0, acc, 0, 0, 0);
            acc = __builtin_amdgcn_mfma_f32_16x16x32_bf16(aQr[1], cb1, acc, 0, 0, 0);
            int tp = nt * 16 + l15;
#pragma unroll
            for (int rg = 0; rg < 4; ++rg) {
                int il = l4 * 4 + rg;
                int j = tp - 15 + il;
                if ((unsigned)j < 1024u)
                    sS[il * 1024 + (j ^ ((il & 7) << 3))] = f2bf(acc[rg]);
            }
            cb0 = nb0; cb1 = nb1; nt = nn;
        }
    }
    __syncthreads();

    // ---- Phase B: content MFMA + epilogue (kh + cls prefetched) ----
    {
        bfrag aQw[2];
#pragma unroll
        for (int ks = 0; ks < 2; ++ks)
            aQw[ks] = *(const bfrag*)&sQw[l15 * 64 + ks * 32 + l4 * 8];
        int jt = w;
        bfrag cb0, cb1; ushort_t ccls[4];
        {
            size_t jrow = (size_t)(b * S_LEN + jt * 16 + l15);
            const ushort_t* kp = &kh[jrow * 768 + n * 64 + l4 * 8];
            cb0 = *(const bfrag*)kp; cb1 = *(const bfrag*)(kp + 32);
            int j = jt * 16 + l15;
#pragma unroll
            for (int rg = 0; rg < 4; ++rg)
                ccls[rg] = clsb[(size_t)(i0 + l4 * 4 + rg) * 1024 + j];
        }
        while (jt < 64) {
            int jn = jt + 4;
            bfrag nb0, nb1; ushort_t ncls[4];
            if (jn < 64) {
                size_t jrow = (size_t)(b * S_LEN + jn * 16 + l15);
                const ushort_t* kp = &kh[jrow * 768 + n * 64 + l4 * 8];
                nb0 = *(const bfrag*)kp; nb1 = *(const bfrag*)(kp + 32);
                int j2 = jn * 16 + l15;
#pragma unroll
                for (int rg = 0; rg < 4; ++rg)
                    ncls[rg] = clsb[(size_t)(i0 + l4 * 4 + rg) * 1024 + j2];
            }
            int j = jt * 16 + l15;
            float am = bf2f(sAm[j]);
            f32x4 acc = {0, 0, 0, 0};
            acc = __builtin_amdgcn_mfma_f32_16x16x32_bf16(aQw[0], cb0, acc, 0, 0, 0);
            acc = __builtin_amdgcn_mfma_f32_16x16x32_bf16(aQw[1], cb1, acc, 0, 0, 0);
#pragma unroll
            for (int rg = 0; rg < 4; ++rg) {
                int il = l4 * 4 + rg;
                int sidx = il * 1024 + (j ^ ((il & 7) << 3));
                float pos = bf2f(sS[sidx]);
                u64_t tw = sTT[il * 16 + (j >> 6)];
                float ttv = ((tw >> (j & 63)) & 1ull) ? sSame[il] : sDiff[il];
                float s = acc[rg] + (pos + ttv) * bf2f(ccls[rg]) + am;
                sS[sidx] = f2bf(s);
            }
            cb0 = nb0; cb1 = nb1;
#pragma unroll
            for (int rg = 0; rg < 4; ++rg) ccls[rg] = ncls[rg];
            jt = jn;
        }
    }
    __syncthreads();

    // ---- softmax per row (16 rows, 16 threads/row) ----
    {
        int row = tid >> 4, sub = tid & 15;
        ushort_t* rp = &sS[row * 1024];
        int rsw = row & 7;
        float m = -3.0e38f;
#pragma unroll
        for (int e = 0; e < 8; ++e) {
            int c = (sub + 16 * e) ^ rsw;
            bfrag v = *(const bfrag*)&rp[c * 8];
#pragma unroll
            for (int q = 0; q < 8; ++q) m = fmaxf(m, bf2f((ushort_t)v[q]));
        }
#pragma unroll
        for (int off = 1; off < 16; off <<= 1) m = fmaxf(m, __shfl_xor(m, off, 16));
        float sum = 0.0f;
#pragma unroll
        for (int e = 0; e < 8; ++e) {
            int c = (sub + 16 * e) ^ rsw;
            bfrag v = *(const bfrag*)&rp[c * 8];
            bfrag st;
#pragma unroll
            for (int q = 0; q < 8; ++q) {
                float ev = __expf(bf2f((ushort_t)v[q]) - m);
                sum += ev;
                st[q] = (short)f2bf(ev);
            }
            *(bfrag*)&rp[c * 8] = st;
        }
#pragma unroll
        for (int off = 1; off < 16; off <<= 1) sum += __shfl_xor(sum, off, 16);
        float inv = 1.0f / sum;
#pragma unroll
        for (int e = 0; e < 8; ++e) {
            int c = (sub + 16 * e) ^ rsw;
            bfrag v = *(const bfrag*)&rp[c * 8];
            bfrag st;
#pragma unroll
            for (int q = 0; q < 8; ++q) st[q] = (short)f2bf(bf2f((ushort_t)v[q]) * inv);
            *(bfrag*)&rp[c * 8] = st;
        }
    }
    __syncthreads();

    // ---- PV: attn_vec = P @ V (wave w owns h-cols [w*16, w*16+16)) ----
    {
        const ushort_t* vbase = vt + (((size_t)b * NHEAD + n) * 64 + w * 16 + l15) * 1024;
        f32x4 acc = {0, 0, 0, 0};
        bfrag cv = *(const bfrag*)&vbase[l4 * 8];
        for (int ks = 0; ks < 32; ++ks) {
            bfrag nv;
            if (ks < 31) nv = *(const bfrag*)&vbase[(ks + 1) * 32 + l4 * 8];
            bfrag pa = *(const bfrag*)&sS[l15 * 1024 + (((ks * 4 + l4) ^ (l15 & 7)) * 8)];
            acc = __builtin_amdgcn_mfma_f32_16x16x32_bf16(pa, cv, acc, 0, 0, 0);
            cv = nv;
        }
#pragma unroll
        for (int rg = 0; rg < 4; ++rg) {
            size_t i = (size_t)(b * S_LEN + i0 + l4 * 4 + rg);
            av[i * 768 + n * 64 + w * 16 + l15] = f2bf(acc[rg]);
        }
    }
}

// ---------------- residual + layernorm ----------------------------------
__global__ __launch_bounds__(256) void out_ln_kernel(
    const float* __restrict__ query, const float* __restrict__ attn_out,
    const float* __restrict__ g, const float* __restrict__ beta,
    float* __restrict__ out)
{
    __shared__ float sx[768];
    __shared__ float sRed[4];
    int row = blockIdx.x, tid = threadIdx.x;
    int wave = tid >> 6, lane = tid & 63;
    float lsum = 0.0f;
    for (int c = tid; c < 768; c += 256) {
        float x = query[(size_t)row * 768 + c] + attn_out[(size_t)row * 768 + c];
        sx[c] = x;
        lsum += x;
    }
#pragma unroll
    for (int off = 32; off >= 1; off >>= 1) lsum += __shfl_xor(lsum, off);
    if (lane == 0) sRed[wave] = lsum;
    __syncthreads();
    float mu = (sRed[0] + sRed[1] + sRed[2] + sRed[3]) * (1.0f / 768.0f);
    float lvar = 0.0f;
    for (int c = tid; c < 768; c += 256) {
        float d = sx[c] - mu;
        lvar += d * d;
    }
#pragma unroll
    for (int off = 32; off >= 1; off >>= 1) lvar += __shfl_xor(lvar, off);
    __syncthreads();
    if (lane == 0) sRed[wave] = lvar;
    __syncthreads();
    float var = (sRed[0] + sRed[1] + sRed[2] + sRed[3]) * (1.0f / 768.0f);
    float rstd = rsqrtf(var + 1e-9f);
    for (int c = tid; c < 768; c += 256)
        out[(size_t)row * 768 + c] = (sx[c] - mu) * rstd * g[c] + beta[c];
}

extern "C" void kernel_launch(void* const* d_in, const int* in_sizes, int n_in,
                              void* d_out, int out_size, void* d_ws, size_t ws_size,
                              hipStream_t stream)
{
    const float* query = (const float*)d_in[0];
    const float* key   = (const float*)d_in[1];
    const float* value = (const float*)d_in[2];
    const float* r     = (const float*)d_in[3];
    const float* cls_mask = (const float*)d_in[4];
    const int*   tt_mat   = (const int*)d_in[5];
    const int*   amask    = (const int*)d_in[6];
    const float* wq  = (const float*)d_in[7];
    const float* wk  = (const float*)d_in[8];
    const float* bk  = (const float*)d_in[9];
    const float* wv  = (const float*)d_in[10];
    const float* bv  = (const float*)d_in[11];
    const float* rwb = (const float*)d_in[12];
    const float* rrb = (const float*)d_in[13];
    const float* rsb = (const float*)d_in[14];
    const float* rk  = (const float*)d_in[15];
    const float* seg = (const float*)d_in[16];
    const float* wo  = (const float*)d_in[17];
    const float* bo  = (const float*)d_in[18];
    const float* lng = (const float*)d_in[19];
    const float* lnb = (const float*)d_in[20];
    float* out = (float*)d_out;

    char* W = (char*)d_ws;
    float*    qh  = (float*)W;                       // +6291456
    ushort_t* kh  = (ushort_t*)(W + 6291456);        // +3145728
    ushort_t* vt  = (ushort_t*)(W + 9437184);        // +3145728
    ushort_t* rh  = (ushort_t*)(W + 12582912);       // +3170304 (2064 rows)
    ushort_t* av  = (ushort_t*)(W + 15753216);       // +3145728
    ushort_t* wqT = (ushort_t*)(W + 18898944);       // +1179648
    ushort_t* wkT = (ushort_t*)(W + 20078592);
    ushort_t* wvT = (ushort_t*)(W + 21258240);
    ushort_t* rkT = (ushort_t*)(W + 22437888);
    ushort_t* woT = (ushort_t*)(W + 23617536);       // ends 24797184
    ushort_t* clsb = (ushort_t*)(W + 24797184);      // +2097152
    u64_t*    ttb  = (u64_t*)(W + 26894336);         // +262144
    float* attn_out = (float*)(W + 27156480);        // +6291456 -> 33447936

    hipLaunchKernelGGL(pack_masks, dim3(1024, 2), dim3(256), 0, stream,
                       cls_mask, tt_mat, clsb, ttb);

    TJobs tj;
    tj.src[0] = wq; tj.dst[0] = wqT;
    tj.src[1] = wk; tj.dst[1] = wkT;
    tj.src[2] = wv; tj.dst[2] = wvT;
    tj.src[3] = rk; tj.dst[3] = rkT;
    tj.src[4] = wo; tj.dst[4] = woT;
    hipLaunchKernelGGL(tcvt_multi, dim3(12, 12, 5), dim3(256), 0, stream, tj);

    GemmJobs4 pj;
    pj.j[0] = {query, nullptr, wqT, nullptr, qh, nullptr, SCALE, 0};
    pj.j[1] = {key,   nullptr, wkT, bk, nullptr, kh, 1.0f, 1};
    pj.j[2] = {value, nullptr, wvT, bv, nullptr, vt, 1.0f, 2};
    pj.j[3] = {r,     nullptr, rkT, nullptr, nullptr, rh, 1.0f, 1};
    hipLaunchKernelGGL(gemm_batch, dim3(32, 12, 4), dim3(256), 0, stream, pj);

    hipLaunchKernelGGL(attn_mfma, dim3(64, 12, 2), dim3(256), 0, stream,
                       qh, kh, vt, rh, rwb, rrb, rsb, seg, clsb, ttb, amask, av);

    GemmJobs4 oj;
    oj.j[0] = {nullptr, av, woT, bo, attn_out, nullptr, 1.0f, 0};
    oj.j[1] = oj.j[0]; oj.j[2] = oj.j[0]; oj.j[3] = oj.j[0];
    hipLaunchKernelGGL(gemm_batch, dim3(32, 12, 1), dim3(256), 0, stream, oj);

    hipLaunchKernelGGL(out_ln_kernel, dim3(2048), dim3(256), 0, stream,
                       query, attn_out, lng, lnb, out);
}